// Round 3
// baseline (15786.751 us; speedup 1.0000x reference)
//
#include <hip/hip_runtime.h>
#include <math.h>

// SARABrainCore: 16-step spiking recurrent net, B=1024 T=16 D=1024 H=2048 O=1024.
// R3: inputs are fp32 (proven: bf16 interpretation NaNs, fp32 finite); outputs
// written as fp32 (stub doc: d_out is the reference's output dtype = float32;
// round-2's absmax=454.0 == zero-buffer attr error proves the harness read
// fp32 words past my 2-byte writes). Internals stay fp64: the spike threshold
// (new_v > 1.0) is chaotic; fp64 tracks an fp64 numpy ref to ~1e-13.
// Fusion: inp@Wfc = x@(Wp@Wfc): precompute Wpf[D,H] fp64, bpf[h]=bp@Wfc+bfc.
// ws ~101 MB: Wpf + bpf + rec + attrA/B + ctx + gated + spkcnt.

#define BB 1024
#define TT 16
#define DD 1024
#define HH 2048
#define OO 1024

// ---- element readers for the GEMM core ----
struct RdF {                               // fp32 input array
    const float* p; long ld;
    __device__ double operator()(int r, int c) const { return (double)p[(long)r*ld + c]; }
};
struct RdD {                               // fp64 internal array
    const double* p; long ld;
    __device__ double operator()(int r, int c) const { return p[(long)r*ld + c]; }
};
struct RdSum {                             // ctx + rec computed on the fly (exact)
    const double* a; const double* b; long ld;
    __device__ double operator()(int r, int c) const { long i=(long)r*ld+c; return a[i]+b[i]; }
};
struct RdSpk {                             // spike count -> mean (x0.0625 exact)
    const float* p; long ld;
    __device__ double operator()(int r, int c) const { return (double)p[(long)r*ld+c] * 0.0625; }
};

// ---- fp64 tiled GEMM core: 64x64 tile, 256 thr, 4x4/thr, BK=16 ----
template<typename AR, typename BR>
__device__ __forceinline__ void gemm_core(AR A, BR B, int row0, int col0, int K,
                                          double* __restrict__ As,
                                          double* __restrict__ Bs,
                                          double acc[4][4])
{
    const int tid = threadIdx.x;
    const int tx = tid & 15, ty = tid >> 4;
    const int am = tid >> 2, ak = (tid & 3) << 2;   // A loader: 64 rows x 16 k
    const int bk = tid >> 4, bn = (tid & 15) << 2;  // B loader: 16 k x 64 cols
    for (int k0 = 0; k0 < K; k0 += 16) {
        double a0 = A(row0+am, k0+ak+0), a1 = A(row0+am, k0+ak+1);
        double a2 = A(row0+am, k0+ak+2), a3 = A(row0+am, k0+ak+3);
        double b0 = B(k0+bk, col0+bn+0), b1 = B(k0+bk, col0+bn+1);
        double b2 = B(k0+bk, col0+bn+2), b3 = B(k0+bk, col0+bn+3);
        __syncthreads();              // prev iter's compute done before LDS overwrite
        As[(ak+0)*64 + am] = a0;
        As[(ak+1)*64 + am] = a1;
        As[(ak+2)*64 + am] = a2;
        As[(ak+3)*64 + am] = a3;
        Bs[bk*64 + bn+0] = b0;
        Bs[bk*64 + bn+1] = b1;
        Bs[bk*64 + bn+2] = b2;
        Bs[bk*64 + bn+3] = b3;
        __syncthreads();
        #pragma unroll
        for (int kk = 0; kk < 16; ++kk) {
            double av[4], bv[4];
            #pragma unroll
            for (int i = 0; i < 4; ++i) av[i] = As[kk*64 + ty*4 + i];
            #pragma unroll
            for (int j = 0; j < 4; ++j) bv[j] = Bs[kk*64 + tx*4 + j];
            #pragma unroll
            for (int i = 0; i < 4; ++i)
                #pragma unroll
                for (int j = 0; j < 4; ++j)
                    acc[i][j] = fma(av[i], bv[j], acc[i][j]);
        }
    }
}

// ---- Wpf = Wp @ Wfc ----
__global__ __launch_bounds__(256) void k_wpf(const float* __restrict__ Wp,
                                             const float* __restrict__ Wfc,
                                             double* __restrict__ Wpf)
{
    __shared__ double As[1024], Bs[1024];
    double acc[4][4] = {};
    int row0 = blockIdx.y*64, col0 = blockIdx.x*64;
    gemm_core(RdF{Wp, HH}, RdF{Wfc, HH}, row0, col0, HH, As, Bs, acc);
    int tx = threadIdx.x & 15, ty = threadIdx.x >> 4;
    for (int i=0;i<4;i++) for (int j=0;j<4;j++)
        Wpf[(long)(row0+ty*4+i)*HH + col0+tx*4+j] = acc[i][j];
}

// ---- bpf[h] = bp @ Wfc + bfc ----
__global__ __launch_bounds__(256) void k_bpf(const float* __restrict__ bp,
                                             const float* __restrict__ Wfc,
                                             const float* __restrict__ bfc,
                                             double* __restrict__ bpf)
{
    int h = blockIdx.x*256 + threadIdx.x;
    double acc = 0.0;
    for (int k = 0; k < HH; ++k)
        acc = fma((double)bp[k], (double)Wfc[(long)k*HH + h], acc);
    bpf[h] = acc + (double)bfc[h];
}

// ---- update = tanh(x_t @ Wpf + bpf); rec = BETA*rec + (1-BETA)*update ----
__global__ __launch_bounds__(256) void k_update(const float* __restrict__ x, int t,
                                                const double* __restrict__ Wpf,
                                                const double* __restrict__ bpf,
                                                double* __restrict__ rec)
{
    __shared__ double As[1024], Bs[1024];
    double acc[4][4] = {};
    int row0 = blockIdx.y*64, col0 = blockIdx.x*64;
    const float* x_t = x + (long)t*DD;              // row b at x[b*T*D + t*D]
    gemm_core(RdF{x_t, (long)TT*DD}, RdD{Wpf, HH}, row0, col0, DD, As, Bs, acc);
    int tx = threadIdx.x & 15, ty = threadIdx.x >> 4;
    const double BETA = 0.9;
    const double OMB  = 1.0 - BETA;   // 0.09999999999999998, Python fp64 semantics
    for (int i=0;i<4;i++) for (int j=0;j<4;j++) {
        int b = row0+ty*4+i, h = col0+tx*4+j;
        double u = tanh(acc[i][j] + bpf[h]);
        long idx = (long)b*HH + h;
        rec[idx] = BETA*rec[idx] + OMB*u;
    }
}

// ---- LayerNorm(rec) -> ctx  (one block per row) ----
__global__ __launch_bounds__(256) void k_ln(const double* __restrict__ rec,
                                            const float* __restrict__ gamma,
                                            const float* __restrict__ beta,
                                            double* __restrict__ ctx)
{
    __shared__ double red[256];
    int b = blockIdx.x, tid = threadIdx.x;
    const double* r = rec + (long)b*HH;
    double s = 0.0;
    for (int h = tid; h < HH; h += 256) s += r[h];
    red[tid] = s; __syncthreads();
    for (int off = 128; off > 0; off >>= 1) {
        if (tid < off) red[tid] += red[tid+off];
        __syncthreads();
    }
    double mean = red[0] / HH;
    __syncthreads();
    double v = 0.0;
    for (int h = tid; h < HH; h += 256) { double d = r[h]-mean; v += d*d; }
    red[tid] = v; __syncthreads();
    for (int off = 128; off > 0; off >>= 1) {
        if (tid < off) red[tid] += red[tid+off];
        __syncthreads();
    }
    double sd = sqrt(red[0] / HH + 1e-5);
    for (int h = tid; h < HH; h += 256) {
        long idx = (long)b*HH + h;
        ctx[idx] = (r[h]-mean)/sd * (double)gamma[h] + (double)beta[h];
    }
}

// ---- g = sigmoid((ctx+rec) @ Wg + bg); gated = g*ctx + (1-g)*rec ----
__global__ __launch_bounds__(256) void k_gate(const double* __restrict__ ctx,
                                              const double* __restrict__ rec,
                                              const float* __restrict__ Wg,
                                              const float* __restrict__ bg,
                                              double* __restrict__ gated)
{
    __shared__ double As[1024], Bs[1024];
    double acc[4][4] = {};
    int row0 = blockIdx.y*64, col0 = blockIdx.x*64;
    gemm_core(RdSum{ctx, rec, HH}, RdF{Wg, HH}, row0, col0, HH, As, Bs, acc);
    int tx = threadIdx.x & 15, ty = threadIdx.x >> 4;
    for (int i=0;i<4;i++) for (int j=0;j<4;j++) {
        int b = row0+ty*4+i, h = col0+tx*4+j;
        long idx = (long)b*HH + h;
        double g = 1.0/(1.0 + exp(-(acc[i][j] + (double)bg[h])));
        gated[idx] = g*ctx[idx] + (1.0-g)*rec[idx];
    }
}

// ---- current = gated@Wenc + attr@Wrec + benc + brec; LIF + spike count ----
__global__ __launch_bounds__(256) void k_current(const double* __restrict__ gated,
                                                 const float* __restrict__ Wenc,
                                                 const double* __restrict__ attr_in,
                                                 const float* __restrict__ Wrec,
                                                 const float* __restrict__ benc,
                                                 const float* __restrict__ brec,
                                                 double* __restrict__ attr_out,
                                                 float* __restrict__ spkcnt)
{
    __shared__ double As[1024], Bs[1024];
    double acc[4][4] = {};
    int row0 = blockIdx.y*64, col0 = blockIdx.x*64;
    gemm_core(RdD{gated,   HH}, RdF{Wenc, HH}, row0, col0, HH, As, Bs, acc);
    gemm_core(RdD{attr_in, HH}, RdF{Wrec, HH}, row0, col0, HH, As, Bs, acc);
    int tx = threadIdx.x & 15, ty = threadIdx.x >> 4;
    const double TAU = 2.0, THR = 1.0;
    for (int i=0;i<4;i++) for (int j=0;j<4;j++) {
        int b = row0+ty*4+i, h = col0+tx*4+j;
        long idx = (long)b*HH + h;
        double cur = acc[i][j] + (double)benc[h] + (double)brec[h];
        double a   = attr_in[idx];
        double nv  = a + (cur - a)/TAU;
        double sp  = (nv > THR) ? 1.0 : 0.0;
        attr_out[idx] = nv - sp*THR;
        spkcnt[idx] += (float)sp;
    }
}

// ---- out = (spkcnt/16) @ Wro + bro -> fp32 ----
__global__ __launch_bounds__(256) void k_readout(const float* __restrict__ spkcnt,
                                                 const float* __restrict__ Wro,
                                                 const float* __restrict__ bro,
                                                 float* __restrict__ out)
{
    __shared__ double As[1024], Bs[1024];
    double acc[4][4] = {};
    int row0 = blockIdx.y*64, col0 = blockIdx.x*64;
    gemm_core(RdSpk{spkcnt, HH}, RdF{Wro, OO}, row0, col0, HH, As, Bs, acc);
    int tx = threadIdx.x & 15, ty = threadIdx.x >> 4;
    for (int i=0;i<4;i++) for (int j=0;j<4;j++) {
        int b = row0+ty*4+i, o = col0+tx*4+j;
        out[(long)b*OO + o] = (float)(acc[i][j] + (double)bro[o]);
    }
}

__global__ __launch_bounds__(256) void k_d2f(const double* __restrict__ src,
                                             float* __restrict__ dst)
{
    long i = (long)blockIdx.x*256 + threadIdx.x;
    dst[i] = (float)src[i];
}

extern "C" void kernel_launch(void* const* d_in, const int* in_sizes, int n_in,
                              void* d_out, int out_size, void* d_ws, size_t ws_size,
                              hipStream_t stream) {
    const float* x    = (const float*)d_in[0];
    const float* Wp   = (const float*)d_in[1];
    const float* bp   = (const float*)d_in[2];
    const float* Wfc  = (const float*)d_in[3];
    const float* bfc  = (const float*)d_in[4];
    const float* gamma= (const float*)d_in[5];
    const float* beta = (const float*)d_in[6];
    const float* Wg   = (const float*)d_in[7];
    const float* bg   = (const float*)d_in[8];
    const float* Wenc = (const float*)d_in[9];
    const float* benc = (const float*)d_in[10];
    const float* Wrec = (const float*)d_in[11];
    const float* brec = (const float*)d_in[12];
    const float* Wro  = (const float*)d_in[13];
    const float* bro  = (const float*)d_in[14];
    float* out = (float*)d_out;

    const long NBH = (long)BB*HH;     // 2M elems
    char* p = (char*)d_ws;
    double* Wpf   = (double*)p; p += (long)DD*HH*sizeof(double);   // 16.8 MB
    double* bpf   = (double*)p; p += HH*sizeof(double);
    double* rec   = (double*)p; p += NBH*sizeof(double);           // 16.8 MB
    double* attrA = (double*)p; p += NBH*sizeof(double);           // 16.8 MB
    double* attrB = (double*)p; p += NBH*sizeof(double);           // 16.8 MB
    double* ctx   = (double*)p; p += NBH*sizeof(double);           // 16.8 MB
    double* gated = (double*)p; p += NBH*sizeof(double);           // 16.8 MB
    float*  spkcnt= (float*)p;  p += NBH*sizeof(float);            // 8.4 MB
    // total ~101 MB

    hipMemsetAsync(rec,    0, NBH*sizeof(double), stream);
    hipMemsetAsync(attrA,  0, NBH*sizeof(double), stream);
    hipMemsetAsync(spkcnt, 0, NBH*sizeof(float),  stream);

    dim3 blk(256);
    dim3 g_wpf(HH/64, DD/64);   // 32 x 16
    k_wpf<<<g_wpf, blk, 0, stream>>>(Wp, Wfc, Wpf);
    k_bpf<<<HH/256, blk, 0, stream>>>(bp, Wfc, bfc, bpf);

    dim3 g_step(HH/64, BB/64);  // 32 x 16
    double* ain  = attrA;
    double* aout = attrB;
    for (int t = 0; t < TT; ++t) {
        k_update <<<g_step, blk, 0, stream>>>(x, t, Wpf, bpf, rec);
        k_ln     <<<BB,     blk, 0, stream>>>(rec, gamma, beta, ctx);
        k_gate   <<<g_step, blk, 0, stream>>>(ctx, rec, Wg, bg, gated);
        k_current<<<g_step, blk, 0, stream>>>(gated, Wenc, ain, Wrec, benc, brec, aout, spkcnt);
        double* tmp = ain; ain = aout; aout = tmp;
    }
    // final attractor state in `ain`

    dim3 g_ro(OO/64, BB/64);    // 16 x 16
    k_readout<<<g_ro, blk, 0, stream>>>(spkcnt, Wro, bro, out);
    k_d2f<<<NBH/256, blk, 0, stream>>>(rec, out + (long)BB*OO);
    k_d2f<<<NBH/256, blk, 0, stream>>>(ain, out + (long)BB*OO + NBH);
}